// Round 1
// baseline (1414.171 us; speedup 1.0000x reference)
//
#include <hip/hip_runtime.h>

#define B_      4
#define CIN     512
#define COUT    512
#define L_      4096
#define K_      7
#define OUT_LEN 4090
#define BM      64
#define BN      64
#define BC      8          // channels per K-chunk
#define TT      (BC * K_)  // 56 = GEMM-K per chunk

__global__ __launch_bounds__(256, 2)
void deform_conv1d_kernel(const float* __restrict__ x,
                          const float* __restrict__ offsets,
                          const float* __restrict__ weight,
                          const float* __restrict__ bias,
                          float* __restrict__ out) {
    const int o0  = blockIdx.x * BN;
    const int d0  = blockIdx.y * BM;
    const int b   = blockIdx.z;
    const int tid = threadIdx.x;

    __shared__ int   SU [BN * K_];          // u0 relative to o0, in [0,69]
    __shared__ float SG0[BN * K_];
    __shared__ float SG1[BN * K_];
    __shared__ float XT [BC][BN + 8];       // x slab: BC channels x 71 cols (pad->72)
    __shared__ float S  [BC][K_][BN];       // interpolated samples, o contiguous
    __shared__ float WT [BM][TT + 1];       // weight chunk, pad 56->57 (bank spread)

    // ---- stage interpolation params (once per block) ----
    for (int e = tid; e < BN * K_; e += 256) {
        const int ol = e / K_;
        const int k  = e % K_;
        const int o  = o0 + ol;
        int   u0rel = 0;
        float g0 = 0.f, g1 = 0.f;
        if (o < OUT_LEN) {
            const float t0  = (float)o;
            const float off = offsets[(size_t)b * OUT_LEN * K_ + (size_t)o * K_ + k];
            float T = t0 + (float)k + off;
            T = fmaxf(T, t0);
            T = fminf(T, t0 + (float)(K_ - 1));
            int u0 = (int)floorf(T);
            if (u0 > L_ - 2) u0 = L_ - 2;   // u0 >= 0 guaranteed (T >= t0 >= 0)
            g0 = fmaxf(1.0f - fabsf((float)u0       - T), 0.0f);
            g1 = fmaxf(1.0f - fabsf((float)(u0 + 1) - T), 0.0f);
            u0rel = u0 - o0;                // in [ol, ol+6] subset of [0, 69]
        }
        SU[e] = u0rel; SG0[e] = g0; SG1[e] = g1;
    }

    float acc[4][4];
    #pragma unroll
    for (int i = 0; i < 4; ++i)
        #pragma unroll
        for (int j = 0; j < 4; ++j) acc[i][j] = 0.f;

    const int ty = tid >> 4;   // 0..15 -> d rows ty*4..ty*4+3
    const int tx = tid & 15;   // 0..15 -> o cols tx*4..tx*4+3
    const float* xb = x + (size_t)b * CIN * L_;

    for (int c0 = 0; c0 < CIN; c0 += BC) {
        __syncthreads();  // protect LDS from previous chunk's readers

        // ---- stage x slab (coalesced along columns) ----
        for (int e = tid; e < BC * (BN + 7); e += 256) {
            const int cl  = e / (BN + 7);
            const int j   = e % (BN + 7);
            const int pos = o0 + j;
            XT[cl][j] = (pos < L_) ? xb[(size_t)(c0 + cl) * L_ + pos] : 0.f;
        }
        // ---- stage weight chunk: W[d0+d][c0*7 + t], t contiguous in memory ----
        for (int e = tid; e < BM * TT; e += 256) {
            const int d = e / TT;
            const int t = e % TT;
            WT[d][t] = weight[(size_t)(d0 + d) * (CIN * K_) + c0 * K_ + t];
        }
        __syncthreads();

        // ---- materialize samp tile (shared across all 64 d's) ----
        for (int e = tid; e < BC * K_ * BN; e += 256) {
            const int cl = e / (K_ * BN);
            const int r  = e % (K_ * BN);
            const int k  = r / BN;
            const int ol = r % BN;
            const int p  = ol * K_ + k;
            const int u  = SU[p];
            S[cl][k][ol] = SG0[p] * XT[cl][u] + SG1[p] * XT[cl][u + 1];
        }
        __syncthreads();

        // ---- register-tile GEMM: 56 K-steps, 16 FMA each ----
        #pragma unroll
        for (int t = 0; t < TT; ++t) {
            const int cl = t / K_;
            const int k  = t % K_;
            const float4 s4 = *(const float4*)&S[cl][k][tx * 4];
            const float w0 = WT[ty * 4 + 0][t];
            const float w1 = WT[ty * 4 + 1][t];
            const float w2 = WT[ty * 4 + 2][t];
            const float w3 = WT[ty * 4 + 3][t];
            acc[0][0] += w0 * s4.x; acc[0][1] += w0 * s4.y; acc[0][2] += w0 * s4.z; acc[0][3] += w0 * s4.w;
            acc[1][0] += w1 * s4.x; acc[1][1] += w1 * s4.y; acc[1][2] += w1 * s4.z; acc[1][3] += w1 * s4.w;
            acc[2][0] += w2 * s4.x; acc[2][1] += w2 * s4.y; acc[2][2] += w2 * s4.z; acc[2][3] += w2 * s4.w;
            acc[3][0] += w3 * s4.x; acc[3][1] += w3 * s4.y; acc[3][2] += w3 * s4.z; acc[3][3] += w3 * s4.w;
        }
    }

    // ---- epilogue ----
    #pragma unroll
    for (int i = 0; i < 4; ++i) {
        const int d = d0 + ty * 4 + i;
        const float bv = bias[d];
        #pragma unroll
        for (int j = 0; j < 4; ++j) {
            const int o = o0 + tx * 4 + j;
            if (o < OUT_LEN)
                out[(size_t)b * COUT * OUT_LEN + (size_t)d * OUT_LEN + o] = acc[i][j] + bv;
        }
    }
}

extern "C" void kernel_launch(void* const* d_in, const int* in_sizes, int n_in,
                              void* d_out, int out_size, void* d_ws, size_t ws_size,
                              hipStream_t stream) {
    const float* x       = (const float*)d_in[0];
    const float* offsets = (const float*)d_in[1];
    const float* weight  = (const float*)d_in[2];
    const float* bias    = (const float*)d_in[3];
    float* out = (float*)d_out;

    dim3 grid((OUT_LEN + BN - 1) / BN, COUT / BM, B_);
    deform_conv1d_kernel<<<grid, 256, 0, stream>>>(x, offsets, weight, bias, out);
}

// Round 3
// 252.059 us; speedup vs baseline: 5.6105x; 5.6105x over previous
//
#include <hip/hip_runtime.h>
#include <stdint.h>

#define B_      4
#define CIN     512
#define COUT    512
#define L_      4096
#define K_      7
#define OUT_LEN 4090

typedef unsigned short ushort_t;
typedef __attribute__((ext_vector_type(8))) __bf16 bf16x8;
typedef __attribute__((ext_vector_type(4))) float f32x4;

__device__ __forceinline__ uint32_t f2bf(float f) {   // RNE float->bf16 bits
    uint32_t u = __float_as_uint(f);
    return (u + 0x7fffu + ((u >> 16) & 1u)) >> 16;
}

__device__ __forceinline__ void async16(const void* g, void* l) {
    __builtin_amdgcn_global_load_lds(
        (const __attribute__((address_space(1))) unsigned int*)g,
        (__attribute__((address_space(3))) unsigned int*)l, 16, 0, 0);
}

// ---------------- kernel 1: weight reorder+cast: Wr[k][d][c] bf16 ----------------
__global__ __launch_bounds__(256)
void reorder_w_kernel(const float* __restrict__ w, uint32_t* __restrict__ Wr) {
    const int e     = blockIdx.x * 256 + threadIdx.x;   // 3584*256 threads
    const int cpair = e & 255;
    const int rest  = e >> 8;          // 0..3583
    const int d     = rest & 511;
    const int k     = rest >> 9;
    const int c     = cpair * 2;
    const float w0 = w[(size_t)d * 3584 + (size_t)c * 7 + k];
    const float w1 = w[(size_t)d * 3584 + (size_t)(c + 1) * 7 + k];
    Wr[((size_t)(k * 512 + d) << 8) + cpair] = (f2bf(w1) << 16) | f2bf(w0);
}

// ---------------- kernel 2: sampling (im2col) -> samp[b][k][o_loc][c] bf16 ----------------
__global__ __launch_bounds__(256)
void sample_kernel(const float* __restrict__ x, const float* __restrict__ offs,
                   uint32_t* __restrict__ samp_u32, int obase, int SLpad) {
    const int bxl = blockIdx.x;            // o-block within stripe
    const int cg  = blockIdx.y;            // c-group of 128
    const int b   = blockIdx.z;
    const int tid = threadIdx.x;
    const int o0g = obase + bxl * 128;

    __shared__ int   SU [7 * 128];
    __shared__ float SG0[7 * 128];
    __shared__ float SG1[7 * 128];
    __shared__ float X[32][137];

    for (int e = tid; e < 7 * 128; e += 256) {
        const int k  = e >> 7;
        const int ol = e & 127;
        int o = o0g + ol; if (o > OUT_LEN - 1) o = OUT_LEN - 1;
        const float t0  = (float)o;
        const float off = offs[(size_t)b * OUT_LEN * K_ + (size_t)o * K_ + k];
        float T = t0 + (float)k + off;
        T = fmaxf(T, t0);
        T = fminf(T, t0 + 6.0f);
        int u0 = (int)floorf(T);
        if (u0 > L_ - 2) u0 = L_ - 2;
        SG0[e] = fmaxf(1.0f - fabsf((float)u0 - T), 0.0f);
        SG1[e] = fmaxf(1.0f - fabsf((float)(u0 + 1) - T), 0.0f);
        SU[e]  = u0 - o0g;                 // in [0, 134)
    }

    const float* xb = x + (size_t)b * CIN * L_;

    for (int cc = 0; cc < 4; ++cc) {
        const int c0 = cg * 128 + cc * 32;
        __syncthreads();
        for (int e = tid; e < 32 * 135; e += 256) {
            const int cl  = e / 135;
            const int j   = e % 135;
            const int col = o0g + j;
            X[cl][j] = (col < L_) ? xb[(size_t)(c0 + cl) * L_ + col] : 0.0f;
        }
        __syncthreads();
        for (int e = tid; e < 7 * 128 * 16; e += 256) {   // exactly 56 iters
            const int cpair = e & 15;
            const int row   = e >> 4;       // k*128 + ol
            const int k  = row >> 7;
            const int ol = row & 127;
            const int u  = SU[row];
            const float g0 = SG0[row], g1 = SG1[row];
            const int cl = cpair * 2;
            const float s0 = g0 * X[cl][u]     + g1 * X[cl][u + 1];
            const float s1 = g0 * X[cl + 1][u] + g1 * X[cl + 1][u + 1];
            samp_u32[((size_t)((b * 7 + k) * SLpad + bxl * 128 + ol)) * 256
                     + (c0 >> 1) + cpair] = (f2bf(s1) << 16) | f2bf(s0);
        }
    }
}

// ---------------- kernel 3: bf16 MFMA GEMM ----------------
__global__ __launch_bounds__(256)
void gemm_kernel(const ushort_t* __restrict__ Wr, const ushort_t* __restrict__ samp,
                 const float* __restrict__ bias, float* __restrict__ out,
                 int obase, int SLpad) {
    const int bxl  = blockIdx.x;
    const int d0   = blockIdx.y * 128;
    const int b    = blockIdx.z;
    const int tid  = threadIdx.x;
    const int wv   = tid >> 6;
    const int lane = tid & 63;
    const int m16  = lane & 15;
    const int quad = lane >> 4;
    const int wm   = wv >> 1;       // d half
    const int wn   = wv & 1;        // o half

    __shared__ __align__(16) ushort_t A_lds[128 * 32];
    __shared__ __align__(16) ushort_t B_lds[128 * 32];

    f32x4 acc[4][4];
    #pragma unroll
    for (int i = 0; i < 4; ++i)
        #pragma unroll
        for (int j = 0; j < 4; ++j) acc[i][j] = (f32x4){0.f, 0.f, 0.f, 0.f};

    const int dstage = tid >> 2;          // 0..63
    const int cstage = (tid & 3) * 8;

    for (int k = 0; k < 7; ++k) {
        const ushort_t* Wk = Wr   + (size_t)(k * 512 + d0) * 512;
        const ushort_t* Sk = samp + ((size_t)(b * 7 + k) * SLpad + bxl * 128) * 512;
        for (int cc = 0; cc < 16; ++cc) {
            const int c0 = cc * 32;
            __syncthreads();
            async16(Wk + (size_t)(dstage)      * 512 + c0 + cstage, A_lds + wv * 512);
            async16(Wk + (size_t)(dstage + 64) * 512 + c0 + cstage, A_lds + 2048 + wv * 512);
            async16(Sk + (size_t)(dstage)      * 512 + c0 + cstage, B_lds + wv * 512);
            async16(Sk + (size_t)(dstage + 64) * 512 + c0 + cstage, B_lds + 2048 + wv * 512);
            __syncthreads();

            bf16x8 af[4], bfr[4];
            #pragma unroll
            for (int i = 0; i < 4; ++i)
                af[i]  = *(const bf16x8*)&A_lds[(wm * 64 + i * 16 + m16) * 32 + quad * 8];
            #pragma unroll
            for (int j = 0; j < 4; ++j)
                bfr[j] = *(const bf16x8*)&B_lds[(wn * 64 + j * 16 + m16) * 32 + quad * 8];
            #pragma unroll
            for (int i = 0; i < 4; ++i)
                #pragma unroll
                for (int j = 0; j < 4; ++j)
                    acc[i][j] = __builtin_amdgcn_mfma_f32_16x16x32_bf16(af[i], bfr[j], acc[i][j], 0, 0, 0);
        }
    }

    const int o0g = obase + bxl * 128;
    #pragma unroll
    for (int i = 0; i < 4; ++i) {
        const int dd = d0 + wm * 64 + i * 16 + quad * 4;
        float bv[4];
        #pragma unroll
        for (int r = 0; r < 4; ++r) bv[r] = bias[dd + r];
        #pragma unroll
        for (int j = 0; j < 4; ++j) {
            const int oo = o0g + wn * 64 + j * 16 + m16;
            if (oo < OUT_LEN) {
                float* op = out + (size_t)b * COUT * OUT_LEN + (size_t)dd * OUT_LEN + oo;
                #pragma unroll
                for (int r = 0; r < 4; ++r)
                    op[(size_t)r * OUT_LEN] = acc[i][j][r] + bv[r];
            }
        }
    }
}

// ---------------- fallback (round-1 fp32 kernel, used only if ws too small) ----------------
#define BM 64
#define BN 64
#define BC 8
#define TT (BC * K_)

__global__ __launch_bounds__(256, 2)
void deform_conv1d_fallback(const float* __restrict__ x, const float* __restrict__ offsets,
                            const float* __restrict__ weight, const float* __restrict__ bias,
                            float* __restrict__ out) {
    const int o0 = blockIdx.x * BN, d0 = blockIdx.y * BM, b = blockIdx.z, tid = threadIdx.x;
    __shared__ int   SU[BN * K_];
    __shared__ float SG0[BN * K_], SG1[BN * K_];
    __shared__ float XT[BC][BN + 8];
    __shared__ float S[BC][K_][BN];
    __shared__ float WT[BM][TT + 1];
    for (int e = tid; e < BN * K_; e += 256) {
        const int ol = e / K_, k = e % K_, o = o0 + ol;
        int u0rel = 0; float g0 = 0.f, g1 = 0.f;
        if (o < OUT_LEN) {
            const float t0 = (float)o;
            const float off = offsets[(size_t)b * OUT_LEN * K_ + (size_t)o * K_ + k];
            float T = fminf(fmaxf(t0 + (float)k + off, t0), t0 + 6.0f);
            int u0 = (int)floorf(T); if (u0 > L_ - 2) u0 = L_ - 2;
            g0 = fmaxf(1.0f - fabsf((float)u0 - T), 0.0f);
            g1 = fmaxf(1.0f - fabsf((float)(u0 + 1) - T), 0.0f);
            u0rel = u0 - o0;
        }
        SU[e] = u0rel; SG0[e] = g0; SG1[e] = g1;
    }
    float acc[4][4];
    #pragma unroll
    for (int i = 0; i < 4; ++i) {
        #pragma unroll
        for (int j = 0; j < 4; ++j) acc[i][j] = 0.f;
    }
    const int ty = tid >> 4, tx = tid & 15;
    const float* xb = x + (size_t)b * CIN * L_;
    for (int c0 = 0; c0 < CIN; c0 += BC) {
        __syncthreads();
        for (int e = tid; e < BC * (BN + 7); e += 256) {
            const int cl = e / (BN + 7), j = e % (BN + 7), pos = o0 + j;
            XT[cl][j] = (pos < L_) ? xb[(size_t)(c0 + cl) * L_ + pos] : 0.f;
        }
        for (int e = tid; e < BM * TT; e += 256) {
            const int d = e / TT, t = e % TT;
            WT[d][t] = weight[(size_t)(d0 + d) * (CIN * K_) + c0 * K_ + t];
        }
        __syncthreads();
        for (int e = tid; e < BC * K_ * BN; e += 256) {
            const int cl = e / (K_ * BN), r = e % (K_ * BN), k = r / BN, ol = r % BN;
            const int p = ol * K_ + k, u = SU[p];
            S[cl][k][ol] = SG0[p] * XT[cl][u] + SG1[p] * XT[cl][u + 1];
        }
        __syncthreads();
        #pragma unroll
        for (int t = 0; t < TT; ++t) {
            const int cl = t / K_, k = t % K_;
            const float4 s4 = *(const float4*)&S[cl][k][tx * 4];
            const float w0 = WT[ty * 4 + 0][t], w1 = WT[ty * 4 + 1][t];
            const float w2 = WT[ty * 4 + 2][t], w3 = WT[ty * 4 + 3][t];
            acc[0][0] += w0 * s4.x; acc[0][1] += w0 * s4.y; acc[0][2] += w0 * s4.z; acc[0][3] += w0 * s4.w;
            acc[1][0] += w1 * s4.x; acc[1][1] += w1 * s4.y; acc[1][2] += w1 * s4.z; acc[1][3] += w1 * s4.w;
            acc[2][0] += w2 * s4.x; acc[2][1] += w2 * s4.y; acc[2][2] += w2 * s4.z; acc[2][3] += w2 * s4.w;
            acc[3][0] += w3 * s4.x; acc[3][1] += w3 * s4.y; acc[3][2] += w3 * s4.z; acc[3][3] += w3 * s4.w;
        }
    }
    #pragma unroll
    for (int i = 0; i < 4; ++i) {
        const int d = d0 + ty * 4 + i;
        const float bvv = bias[d];
        #pragma unroll
        for (int j = 0; j < 4; ++j) {
            const int o = o0 + tx * 4 + j;
            if (o < OUT_LEN)
                out[(size_t)b * COUT * OUT_LEN + (size_t)d * OUT_LEN + o] = acc[i][j] + bvv;
        }
    }
}

extern "C" void kernel_launch(void* const* d_in, const int* in_sizes, int n_in,
                              void* d_out, int out_size, void* d_ws, size_t ws_size,
                              hipStream_t stream) {
    const float* x       = (const float*)d_in[0];
    const float* offsets = (const float*)d_in[1];
    const float* weight  = (const float*)d_in[2];
    const float* bias    = (const float*)d_in[3];
    float* out = (float*)d_out;

    const size_t WR_BYTES   = (size_t)512 * 512 * 7 * 2;        // 3,670,016
    const size_t PER_OBLOCK = (size_t)4 * 7 * 128 * 512 * 2;    // 3,670,016 bytes / o-block
    const int TOTAL_OB = 32;                                     // 4096/128 (o padded)

    long long max_ob = (ws_size > WR_BYTES) ? (long long)((ws_size - WR_BYTES) / PER_OBLOCK) : 0;
    if (max_ob < 1) {
        dim3 grid((OUT_LEN + BN - 1) / BN, COUT / BM, B_);
        deform_conv1d_fallback<<<grid, 256, 0, stream>>>(x, offsets, weight, bias, out);
        return;
    }
    const int nb = (int)(max_ob < TOTAL_OB ? max_ob : TOTAL_OB);
    const int SLpad = nb * 128;
    uint32_t*  Wr_u32 = (uint32_t*)d_ws;
    ushort_t*  Wr     = (ushort_t*)d_ws;
    uint32_t*  samp32 = (uint32_t*)((char*)d_ws + WR_BYTES);
    ushort_t*  samp   = (ushort_t*)((char*)d_ws + WR_BYTES);

    reorder_w_kernel<<<3584, 256, 0, stream>>>(weight, Wr_u32);
    for (int s = 0; s < TOTAL_OB; s += nb) {
        const int cnt = (TOTAL_OB - s) < nb ? (TOTAL_OB - s) : nb;
        sample_kernel<<<dim3(cnt, 4, B_), 256, 0, stream>>>(x, offsets, samp32, s * 128, SLpad);
        gemm_kernel<<<dim3(cnt, 4, B_), 256, 0, stream>>>(Wr, samp, bias, out, s * 128, SLpad);
    }
}

// Round 4
// 234.515 us; speedup vs baseline: 6.0302x; 1.0748x over previous
//
#include <hip/hip_runtime.h>
#include <stdint.h>

#define B_      4
#define CIN     512
#define COUT    512
#define L_      4096
#define K_      7
#define OUT_LEN 4090

typedef unsigned short ushort_t;
typedef __attribute__((ext_vector_type(8))) __bf16 bf16x8;
typedef __attribute__((ext_vector_type(4))) float f32x4;

__device__ __forceinline__ uint32_t f2bf(float f) {   // RNE float->bf16 bits
    uint32_t u = __float_as_uint(f);
    return (u + 0x7fffu + ((u >> 16) & 1u)) >> 16;
}

__device__ __forceinline__ void async16(const void* g, void* l) {
    __builtin_amdgcn_global_load_lds(
        (const __attribute__((address_space(1))) unsigned int*)g,
        (__attribute__((address_space(3))) unsigned int*)l, 16, 0, 0);
}

// ---------------- kernel 1: weight reorder+cast: Wr[k][d][c] bf16 ----------------
__global__ __launch_bounds__(256)
void reorder_w_kernel(const float* __restrict__ w, uint32_t* __restrict__ Wr) {
    const int e     = blockIdx.x * 256 + threadIdx.x;   // 3584*256 threads
    const int cpair = e & 255;
    const int rest  = e >> 8;          // 0..3583
    const int d     = rest & 511;
    const int k     = rest >> 9;
    const int c     = cpair * 2;
    const float w0 = w[(size_t)d * 3584 + (size_t)c * 7 + k];
    const float w1 = w[(size_t)d * 3584 + (size_t)(c + 1) * 7 + k];
    Wr[((size_t)(k * 512 + d) << 8) + cpair] = (f2bf(w1) << 16) | f2bf(w0);
}

// ---------------- kernel 2: fused interp + bf16 MFMA GEMM ----------------
// grid (32 o-blocks, 4 d-blocks, 4 batch), 256 threads (4 waves)
// out-tile 128d x 128o; K = 16 c-chunks x 7 k = 112 steps of 32
__global__ __launch_bounds__(256)
void fused_kernel(const float* __restrict__ x, const float* __restrict__ offs,
                  const ushort_t* __restrict__ Wr, const float* __restrict__ bias,
                  float* __restrict__ out) {
    const int o0   = blockIdx.x * 128;
    const int d0   = blockIdx.y * 128;
    const int b    = blockIdx.z;
    const int tid  = threadIdx.x;
    const int wv   = tid >> 6;
    const int lane = tid & 63;
    const int m16  = lane & 15;
    const int quad = lane >> 4;
    const int wm   = wv >> 1;
    const int wn   = wv & 1;

    // x slab, transposed col-major + pair-XOR swizzle:
    // elem (col, c=2*cp+h) at word col*32 + (((cp ^ (col&15))<<1) | h)
    __shared__ float    XT[136 * 32];                    // 17408 B
    __shared__ __align__(16) uint32_t Sb[2][2048];       // B-tile dbuf: [128 o][16 cpair]
    __shared__ __align__(16) uint32_t Ab[2][2048];       // A-tile dbuf: [128 d][32 c] bf16
    __shared__ int      SU[896];                         // u0 - o0, per (k, ol)
    __shared__ float2   PG[896];                         // (g0, g1)

    // ---- interp params (once per block) ----
    for (int e = tid; e < 896; e += 256) {
        const int k  = e >> 7;
        const int ol = e & 127;
        int o = o0 + ol; if (o > OUT_LEN - 1) o = OUT_LEN - 1;
        const float t0  = (float)o;
        const float off = offs[((size_t)b * OUT_LEN + o) * K_ + k];
        float T = t0 + (float)k + off;
        T = fmaxf(T, t0);
        T = fminf(T, t0 + 6.0f);
        int u0 = (int)floorf(T);
        if (u0 > L_ - 2) u0 = L_ - 2;
        const float g0 = fmaxf(1.0f - fabsf((float)u0 - T), 0.0f);
        const float g1 = fmaxf(1.0f - fabsf((float)(u0 + 1) - T), 0.0f);
        SU[e] = u0 - o0;                  // in [0, 134]
        PG[e] = make_float2(g0, g1);
    }

    f32x4 acc[4][4];
    #pragma unroll
    for (int i = 0; i < 4; ++i) {
        #pragma unroll
        for (int j = 0; j < 4; ++j) acc[i][j] = (f32x4){0.f, 0.f, 0.f, 0.f};
    }

    const int dstage = tid >> 2;          // A staging row 0..63
    const int cstage = (tid & 3) * 8;     // A staging col offset (ushorts)
    const int olr    = tid >> 1;          // S-compute: o row 0..127
    const int half   = tid & 1;           // S-compute: cpair half (0..7 / 8..15)

    const float* xb = x + (size_t)b * CIN * L_ + o0;

    for (int cc = 0; cc < 16; ++cc) {
        // ---- stage XT: 32 channels x 136 cols (prev readers done at last sync) ----
        const float* xc = xb + (size_t)cc * 32 * L_;
        #pragma unroll
        for (int i = 0; i < 5; ++i) {
            const int e = i * 256 + tid;
            if (e < 1088) {                       // 32 c * 34 float4
                const int c    = e / 34;
                const int col4 = e - c * 34;
                const int colb = col4 * 4;
                float4 v;
                if (o0 + colb + 3 < L_) {
                    v = *(const float4*)(xc + (size_t)c * L_ + colb);
                } else {
                    float t0_ = (o0 + colb + 0 < L_) ? xc[(size_t)c * L_ + colb + 0] : 0.f;
                    float t1_ = (o0 + colb + 1 < L_) ? xc[(size_t)c * L_ + colb + 1] : 0.f;
                    float t2_ = (o0 + colb + 2 < L_) ? xc[(size_t)c * L_ + colb + 2] : 0.f;
                    float t3_ = (o0 + colb + 3 < L_) ? xc[(size_t)c * L_ + colb + 3] : 0.f;
                    v = make_float4(t0_, t1_, t2_, t3_);
                }
                const int cp = c >> 1, h = c & 1;
                const float* vf = (const float*)&v;
                #pragma unroll
                for (int ii = 0; ii < 4; ++ii) {
                    const int col = colb + ii;
                    XT[col * 32 + (((cp ^ (col & 15)) << 1) | h)] = vf[ii];
                }
            }
        }
        __syncthreads();   // XT visible to all

        for (int k = 0; k < K_; ++k) {
            const int buf = (cc * K_ + k) & 1;

            // ---- compute B-tile: this thread does (olr, cpairs half*8..+7) ----
            const int   row = (k << 7) | olr;
            const int   u   = SU[row];
            const float2 g  = PG[row];
            const float2* XT2 = (const float2*)XT;
            const int base0 = u * 16, sw0 = u & 15;
            const int base1 = base0 + 16, sw1 = (u + 1) & 15;
            uint32_t r[8];
            #pragma unroll
            for (int j = 0; j < 8; ++j) {
                const int cp = half * 8 + j;
                const float2 lo = XT2[base0 + (cp ^ sw0)];
                const float2 hi = XT2[base1 + (cp ^ sw1)];
                const float s0 = g.x * lo.x + g.y * hi.x;
                const float s1 = g.x * lo.y + g.y * hi.y;
                r[j] = (f2bf(s1) << 16) | f2bf(s0);
            }
            uint32_t* Sw = &Sb[buf][olr * 16 + half * 8];
            *(uint4*)(Sw + 0) = make_uint4(r[0], r[1], r[2], r[3]);
            *(uint4*)(Sw + 4) = make_uint4(r[4], r[5], r[6], r[7]);

            // ---- stage A-tile (async, direct to LDS) ----
            const ushort_t* Wk = Wr + (size_t)(k * 512 + d0) * 512 + cc * 32;
            ushort_t* Al = (ushort_t*)Ab[buf];
            async16(Wk + (size_t)dstage * 512 + cstage,        Al + wv * 512);
            async16(Wk + (size_t)(dstage + 64) * 512 + cstage, Al + 2048 + wv * 512);

            __syncthreads();   // S written, A landed (barrier drains vmcnt)

            // ---- MFMA phase ----
            const ushort_t* As = (const ushort_t*)Ab[buf];
            const ushort_t* Ss = (const ushort_t*)Sb[buf];
            bf16x8 af[4], bfr[4];
            #pragma unroll
            for (int i = 0; i < 4; ++i)
                af[i]  = *(const bf16x8*)&As[(wm * 64 + i * 16 + m16) * 32 + quad * 8];
            #pragma unroll
            for (int j = 0; j < 4; ++j)
                bfr[j] = *(const bf16x8*)&Ss[(wn * 64 + j * 16 + m16) * 32 + quad * 8];
            #pragma unroll
            for (int i = 0; i < 4; ++i) {
                #pragma unroll
                for (int j = 0; j < 4; ++j)
                    acc[i][j] = __builtin_amdgcn_mfma_f32_16x16x32_bf16(af[i], bfr[j], acc[i][j], 0, 0, 0);
            }
        }
    }

    // ---- epilogue (verified layout: col=o via m16, rows=d via quad*4+reg) ----
    #pragma unroll
    for (int i = 0; i < 4; ++i) {
        const int dd = d0 + wm * 64 + i * 16 + quad * 4;
        float bv[4];
        #pragma unroll
        for (int r = 0; r < 4; ++r) bv[r] = bias[dd + r];
        #pragma unroll
        for (int j = 0; j < 4; ++j) {
            const int oo = o0 + wn * 64 + j * 16 + m16;
            if (oo < OUT_LEN) {
                float* op = out + (size_t)b * COUT * OUT_LEN + (size_t)dd * OUT_LEN + oo;
                #pragma unroll
                for (int r = 0; r < 4; ++r)
                    op[(size_t)r * OUT_LEN] = acc[i][j][r] + bv[r];
            }
        }
    }
}

// ---------------- fallback (round-1 fp32 kernel, used only if ws too small) ----------------
#define BM 64
#define BN 64
#define BC 8
#define TT (BC * K_)

__global__ __launch_bounds__(256, 2)
void deform_conv1d_fallback(const float* __restrict__ x, const float* __restrict__ offsets,
                            const float* __restrict__ weight, const float* __restrict__ bias,
                            float* __restrict__ out) {
    const int o0 = blockIdx.x * BN, d0 = blockIdx.y * BM, b = blockIdx.z, tid = threadIdx.x;
    __shared__ int   SU[BN * K_];
    __shared__ float SG0[BN * K_], SG1[BN * K_];
    __shared__ float XT[BC][BN + 8];
    __shared__ float S[BC][K_][BN];
    __shared__ float WT[BM][TT + 1];
    for (int e = tid; e < BN * K_; e += 256) {
        const int ol = e / K_, k = e % K_, o = o0 + ol;
        int u0rel = 0; float g0 = 0.f, g1 = 0.f;
        if (o < OUT_LEN) {
            const float t0 = (float)o;
            const float off = offsets[(size_t)b * OUT_LEN * K_ + (size_t)o * K_ + k];
            float T = fminf(fmaxf(t0 + (float)k + off, t0), t0 + 6.0f);
            int u0 = (int)floorf(T); if (u0 > L_ - 2) u0 = L_ - 2;
            g0 = fmaxf(1.0f - fabsf((float)u0 - T), 0.0f);
            g1 = fmaxf(1.0f - fabsf((float)(u0 + 1) - T), 0.0f);
            u0rel = u0 - o0;
        }
        SU[e] = u0rel; SG0[e] = g0; SG1[e] = g1;
    }
    float acc[4][4];
    #pragma unroll
    for (int i = 0; i < 4; ++i) {
        #pragma unroll
        for (int j = 0; j < 4; ++j) acc[i][j] = 0.f;
    }
    const int ty = tid >> 4, tx = tid & 15;
    const float* xb = x + (size_t)b * CIN * L_;
    for (int c0 = 0; c0 < CIN; c0 += BC) {
        __syncthreads();
        for (int e = tid; e < BC * (BN + 7); e += 256) {
            const int cl = e / (BN + 7), j = e % (BN + 7), pos = o0 + j;
            XT[cl][j] = (pos < L_) ? xb[(size_t)(c0 + cl) * L_ + pos] : 0.f;
        }
        for (int e = tid; e < BM * TT; e += 256) {
            const int d = e / TT, t = e % TT;
            WT[d][t] = weight[(size_t)(d0 + d) * (CIN * K_) + c0 * K_ + t];
        }
        __syncthreads();
        for (int e = tid; e < BC * K_ * BN; e += 256) {
            const int cl = e / (K_ * BN), r = e % (K_ * BN), k = r / BN, ol = r % BN;
            const int p = ol * K_ + k, u = SU[p];
            S[cl][k][ol] = SG0[p] * XT[cl][u] + SG1[p] * XT[cl][u + 1];
        }
        __syncthreads();
        #pragma unroll
        for (int t = 0; t < TT; ++t) {
            const int cl = t / K_, k = t % K_;
            const float4 s4 = *(const float4*)&S[cl][k][tx * 4];
            const float w0 = WT[ty * 4 + 0][t], w1 = WT[ty * 4 + 1][t];
            const float w2 = WT[ty * 4 + 2][t], w3 = WT[ty * 4 + 3][t];
            acc[0][0] += w0 * s4.x; acc[0][1] += w0 * s4.y; acc[0][2] += w0 * s4.z; acc[0][3] += w0 * s4.w;
            acc[1][0] += w1 * s4.x; acc[1][1] += w1 * s4.y; acc[1][2] += w1 * s4.z; acc[1][3] += w1 * s4.w;
            acc[2][0] += w2 * s4.x; acc[2][1] += w2 * s4.y; acc[2][2] += w2 * s4.z; acc[2][3] += w2 * s4.w;
            acc[3][0] += w3 * s4.x; acc[3][1] += w3 * s4.y; acc[3][2] += w3 * s4.z; acc[3][3] += w3 * s4.w;
        }
    }
    #pragma unroll
    for (int i = 0; i < 4; ++i) {
        const int d = d0 + ty * 4 + i;
        const float bvv = bias[d];
        #pragma unroll
        for (int j = 0; j < 4; ++j) {
            const int o = o0 + tx * 4 + j;
            if (o < OUT_LEN)
                out[(size_t)b * COUT * OUT_LEN + (size_t)d * OUT_LEN + o] = acc[i][j] + bvv;
        }
    }
}

extern "C" void kernel_launch(void* const* d_in, const int* in_sizes, int n_in,
                              void* d_out, int out_size, void* d_ws, size_t ws_size,
                              hipStream_t stream) {
    const float* x       = (const float*)d_in[0];
    const float* offsets = (const float*)d_in[1];
    const float* weight  = (const float*)d_in[2];
    const float* bias    = (const float*)d_in[3];
    float* out = (float*)d_out;

    const size_t WR_BYTES = (size_t)512 * 512 * 7 * 2;   // 3,670,016

    if (ws_size < WR_BYTES) {
        dim3 grid((OUT_LEN + BN - 1) / BN, COUT / BM, B_);
        deform_conv1d_fallback<<<grid, 256, 0, stream>>>(x, offsets, weight, bias, out);
        return;
    }

    uint32_t* Wr_u32 = (uint32_t*)d_ws;
    ushort_t* Wr     = (ushort_t*)d_ws;

    reorder_w_kernel<<<3584, 256, 0, stream>>>(weight, Wr_u32);
    fused_kernel<<<dim3(32, 4, B_), 256, 0, stream>>>(x, offsets, Wr, bias, out);
}